// Round 4
// baseline (29.639 us; speedup 1.0000x reference)
//
#include <hip/hip_runtime.h>
#include <math.h>

namespace {
constexpr int NB   = 256;
constexpr int NA   = 64;
constexpr int EMBD = 64;
constexpr int HIDD = 128;
constexpr int OUTD = 512;
constexpr int FPS  = 136;   // short-stride for bf16 LDS tiles: row = 272 B -> 4-bank advance,
                            // A-frag b128 reads land 2-way per bank (free, m136)

typedef __attribute__((ext_vector_type(8))) short bfrag8;   // 8 bf16 = 4 VGPRs
typedef __attribute__((ext_vector_type(4))) float floatx4;  // MFMA accumulator

__device__ __forceinline__ unsigned short bf16_rne(float f) {
    unsigned u = __float_as_uint(f);
    u += 0x7fffu + ((u >> 16) & 1u);
    return (unsigned short)(u >> 16);
}

// branch-free exact-GELU: erf via Abramowitz-Stegun 7.1.26 (|err| <= 1.5e-7)
__device__ __forceinline__ float gelu_fast(float x) {
    const float ax = fabsf(x) * 0.7071067811865475f;   // |x|/sqrt(2)
    const float t  = __builtin_amdgcn_rcpf(fmaf(0.3275911f, ax, 1.0f));
    float p = fmaf(1.061405429f, t, -1.453152027f);
    p = fmaf(p, t, 1.421413741f);
    p = fmaf(p, t, -0.284496736f);
    p = fmaf(p, t, 0.254829592f);
    p = p * t;
    const float e = __builtin_amdgcn_exp2f(-1.4426950408889634f * ax * ax);
    const float erfax = fmaf(-p, e, 1.0f);
    const float erfx  = copysignf(erfax, x);
    const float hx    = 0.5f * x;
    return fmaf(hx, erfx, hx);
}

// ---- weight prep: W1,W2 -> bf16 hi/lo in MFMA B-fragment order, once per launch.
// ws layout (shorts): [0)W1hi [16384)W1lo [32768)W2hi [49152)W2lo
// frag idx = ((ks*8+ntile)*64+lane)*8+r  <->  W[ks*32+(lane>>4)*8+r][ntile*16+(lane&15)]
__global__ __launch_bounds__(256, 4)
void prep_weights(const float* __restrict__ W1, const float* __restrict__ W2,
                  short* __restrict__ ws) {
    const int t = blockIdx.x * 256 + threadIdx.x;       // 32768 threads
    const float* W  = (t < 16384) ? W1 : W2;
    const int  base = (t < 16384) ? 0  : 32768;
    const int  idx  = t & 16383;
    const int  r    = idx & 7;
    const int  lane = (idx >> 3) & 63;
    const int  tile = (idx >> 9) & 7;
    const int  ks   = idx >> 12;
    const int  k    = ks * 32 + (lane >> 4) * 8 + r;
    const int  n    = tile * 16 + (lane & 15);
    const float f   = W[k * HIDD + n];
    const unsigned short h = bf16_rne(f);
    const unsigned short l = bf16_rne(f - __uint_as_float((unsigned)h << 16));
    ws[base + idx]         = (short)h;
    ws[base + 16384 + idx] = (short)l;
}

__global__ __launch_bounds__(1024, 1)
void mlip_fused(const int*   __restrict__ atomic_nums,
                const float* __restrict__ coords,
                const float* __restrict__ embed_table,
                const float* __restrict__ b1,
                const float* __restrict__ b2,
                const float* __restrict__ Wo, const float* __restrict__ bo,
                const float* __restrict__ centers,
                const short* __restrict__ wfrag,
                float*       __restrict__ out)
{
    const int b    = blockIdx.x;
    const int tid  = threadIdx.x;
    const int lane = tid & 63;
    const int wid  = tid >> 6;          // 16 waves

    __shared__ float s_dist[NA * NA];        // 16 KB; reused as stage-6 reduction buffer
    __shared__ short s_fhi[NA][FPS], s_flo[NA][FPS];   // feat as bf16 hi/lo (35 KB)
    __shared__ short s_hhi[NA][FPS], s_hlo[NA][FPS];   // h    as bf16 hi/lo (35 KB)
    __shared__ float s_mol[4][HIDD];
    __shared__ float s_molv[HIDD];

    // ---- MFMA tiling ids (needed early for bias preloads)
    const int wm      = wid & 3, wn = wid >> 2;
    const int lrow    = lane & 15, g4 = lane >> 4;
    const int arow    = (wm << 4) + lrow;
    const int drow0   = (wm << 4) + (g4 << 2);
    const int colbase = (wn << 5) + lrow;

    // ---- early scalar/vector preloads (overlap with front compute)
    const int   col512 = tid & 511, kh = tid >> 9;
    const float bo_r   = bo[col512];
    const float b1a    = b1[colbase];
    const float b1b    = b1[colbase + 16];
    const float b2r    = b2[tid & 127];
    const float c      = centers[lane];

    // per-lane coords of atom `lane`
    const float* cbase = coords + (size_t)b * NA * 3;
    const float cx = cbase[lane * 3 + 0];
    const float cy = cbase[lane * 3 + 1];
    const float cz = cbase[lane * 3 + 2];

    // ---- embedding gather -> s_fhi/s_flo[:, 0:64]
    {
        const int i = tid >> 4, e4 = (tid & 15) << 2;
        const int z = atomic_nums[b * NA + i];
        const float4 ev = *(const float4*)(embed_table + (size_t)z * EMBD + e4);
        short4 h4, l4;
        {
            const float v[4] = {ev.x, ev.y, ev.z, ev.w};
            short* hp = (short*)&h4; short* lp = (short*)&l4;
#pragma unroll
            for (int q = 0; q < 4; ++q) {
                const unsigned short h = bf16_rne(v[q]);
                hp[q] = (short)h;
                lp[q] = (short)bf16_rne(v[q] - __uint_as_float((unsigned)h << 16));
            }
        }
        *(short4*)&s_fhi[i][e4] = h4;
        *(short4*)&s_flo[i][e4] = l4;
    }

    // ---- dist rows this wave will itself consume (within-wave dep only)
#pragma unroll
    for (int it = 0; it < 4; ++it) {
        const int i = wid + (it << 4);
        const float xi = __shfl(cx, i, 64);
        const float yi = __shfl(cy, i, 64);
        const float zi = __shfl(cz, i, 64);
        const float dx = xi - cx, dy = yi - cy, dz = zi - cz;
        const float sq = dx * dx + dy * dy + dz * dz;
        s_dist[(i << 6) + lane] = sq > 0.0f ? sqrtf(sq) : 0.0f;
    }

    // ---- gaussian smear, mean over j -> s_fhi/s_flo[:, 64:128]
    // exp(-2(d-c)^2) = exp2(K2*d^2 - 2*K2*c*d + K2*c^2); 4 independent accumulators
    {
        const float K2  = -2.8853900817779268f;   // -2*log2(e)
        const float nu2 = -2.0f * K2 * c;
        const float vc  = K2 * c * c;
#pragma unroll
        for (int it = 0; it < 4; ++it) {
            const int i = wid + (it << 4);
            const float* drow = &s_dist[i << 6];
            float a0 = 0.f, a1 = 0.f, a2 = 0.f, a3 = 0.f;
#pragma unroll
            for (int j4 = 0; j4 < NA; j4 += 4) {
                const float4 d4 = *(const float4*)(drow + j4);
                a0 += __builtin_amdgcn_exp2f(fmaf(d4.x, fmaf(K2, d4.x, nu2), vc));
                a1 += __builtin_amdgcn_exp2f(fmaf(d4.y, fmaf(K2, d4.y, nu2), vc));
                a2 += __builtin_amdgcn_exp2f(fmaf(d4.z, fmaf(K2, d4.z, nu2), vc));
                a3 += __builtin_amdgcn_exp2f(fmaf(d4.w, fmaf(K2, d4.w, nu2), vc));
            }
            const float acc = ((a0 + a1) + (a2 + a3)) * (1.0f / 64.0f);
            const unsigned short h = bf16_rne(acc);
            s_fhi[i][EMBD + lane] = (short)h;
            s_flo[i][EMBD + lane] =
                (short)bf16_rne(acc - __uint_as_float((unsigned)h << 16));
        }
    }
    __syncthreads();                                   // barrier 1

    const short* w1hi = wfrag;
    const short* w1lo = wfrag + 16384;
    const short* w2hi = wfrag + 32768;
    const short* w2lo = wfrag + 49152;

    // ---- stage 3: h = gelu(feat @ W1 + b1); A-frags read directly as bf16 hi/lo
    {
        floatx4 acc0 = {0,0,0,0}, acc1 = {0,0,0,0};
#pragma unroll
        for (int ks = 0; ks < 4; ++ks) {
            const int k0 = (ks << 5) + (g4 << 3);
            const bfrag8 ahi = *(const bfrag8*)&s_fhi[arow][k0];
            const bfrag8 alo = *(const bfrag8*)&s_flo[arow][k0];
#pragma unroll
            for (int nt = 0; nt < 2; ++nt) {
                const int fidx = (((ks << 3) + (wn << 1) + nt) << 6) + lane;
                const bfrag8 bhi = *(const bfrag8*)&w1hi[fidx << 3];
                const bfrag8 blo = *(const bfrag8*)&w1lo[fidx << 3];
                floatx4 a = nt ? acc1 : acc0;
                a = __builtin_amdgcn_mfma_f32_16x16x32_bf16(ahi, bhi, a, 0, 0, 0);
                a = __builtin_amdgcn_mfma_f32_16x16x32_bf16(ahi, blo, a, 0, 0, 0);
                a = __builtin_amdgcn_mfma_f32_16x16x32_bf16(alo, bhi, a, 0, 0, 0);
                if (nt) acc1 = a; else acc0 = a;
            }
        }
#pragma unroll
        for (int nt = 0; nt < 2; ++nt) {
            const int col = colbase + (nt << 4);
            const float bb = nt ? b1b : b1a;
            const floatx4 a = nt ? acc1 : acc0;
#pragma unroll
            for (int r = 0; r < 4; ++r) {
                const float v = gelu_fast(a[r] + bb);
                const unsigned short h = bf16_rne(v);
                s_hhi[drow0 + r][col] = (short)h;
                s_hlo[drow0 + r][col] =
                    (short)bf16_rne(v - __uint_as_float((unsigned)h << 16));
            }
        }
    }
    __syncthreads();                                   // barrier 2

    // ---- stage 4: h2 = h @ W2, atom-sum folded into shuffle reduction
    float wo_r[64];                                    // Wo prefetch target
    {
        floatx4 acc0 = {0,0,0,0}, acc1 = {0,0,0,0};
#pragma unroll
        for (int ks = 0; ks < 4; ++ks) {
            const int k0 = (ks << 5) + (g4 << 3);
            const bfrag8 ahi = *(const bfrag8*)&s_hhi[arow][k0];
            const bfrag8 alo = *(const bfrag8*)&s_hlo[arow][k0];
#pragma unroll
            for (int nt = 0; nt < 2; ++nt) {
                const int fidx = (((ks << 3) + (wn << 1) + nt) << 6) + lane;
                const bfrag8 bhi = *(const bfrag8*)&w2hi[fidx << 3];
                const bfrag8 blo = *(const bfrag8*)&w2lo[fidx << 3];
                floatx4 a = nt ? acc1 : acc0;
                a = __builtin_amdgcn_mfma_f32_16x16x32_bf16(ahi, bhi, a, 0, 0, 0);
                a = __builtin_amdgcn_mfma_f32_16x16x32_bf16(ahi, blo, a, 0, 0, 0);
                a = __builtin_amdgcn_mfma_f32_16x16x32_bf16(alo, bhi, a, 0, 0, 0);
                if (nt) acc1 = a; else acc0 = a;
            }
        }

        // issue Wo prefetch now: latency hides under reduce + barriers + stage 5
        {
            const float* wop = Wo + ((size_t)(kh << 6)) * OUTD + col512;
#pragma unroll
            for (int k = 0; k < 64; ++k) wo_r[k] = wop[(size_t)k * OUTD];
        }

#pragma unroll
        for (int nt = 0; nt < 2; ++nt) {
            const floatx4 a = nt ? acc1 : acc0;
            float s = a[0] + a[1] + a[2] + a[3];
            s += __shfl_xor(s, 16, 64);
            s += __shfl_xor(s, 32, 64);
            if (lane < 16) s_mol[wm][colbase + (nt << 4)] = s;
        }
    }
    __syncthreads();                                   // barrier 3

    // ---- stage 5: mol = mean + b2
    if (tid < HIDD)
        s_molv[tid] = (s_mol[0][tid] + s_mol[1][tid] + s_mol[2][tid] + s_mol[3][tid])
                      * (1.0f / 64.0f) + b2r;
    __syncthreads();                                   // barrier 4

    // ---- stage 6: out = mol @ Wo + bo (Wo already in registers; pure FMA)
    {
        const float* mp = &s_molv[kh << 6];
        float a = 0.0f;
#pragma unroll
        for (int k = 0; k < 64; k += 4) {
            const float4 m4 = *(const float4*)(mp + k);
            a = fmaf(m4.x, wo_r[k + 0], a);
            a = fmaf(m4.y, wo_r[k + 1], a);
            a = fmaf(m4.z, wo_r[k + 2], a);
            a = fmaf(m4.w, wo_r[k + 3], a);
        }
        s_dist[tid] = a;     // s_dist dead; reuse as reduction buffer
    }
    __syncthreads();                                   // barrier 5
    if (tid < OUTD)
        out[(size_t)b * OUTD + tid] = s_dist[tid] + s_dist[tid + 512] + bo_r;
}
} // namespace

extern "C" void kernel_launch(void* const* d_in, const int* in_sizes, int n_in,
                              void* d_out, int out_size, void* d_ws, size_t ws_size,
                              hipStream_t stream) {
    const int*   atomic_nums = (const int*)  d_in[0];
    const float* coords      = (const float*)d_in[1];
    const float* embed_table = (const float*)d_in[2];
    const float* W1          = (const float*)d_in[3];
    const float* b1          = (const float*)d_in[4];
    const float* W2          = (const float*)d_in[5];
    const float* b2          = (const float*)d_in[6];
    const float* Wo          = (const float*)d_in[7];
    const float* bo          = (const float*)d_in[8];
    const float* centers     = (const float*)d_in[9];
    float*       out         = (float*)d_out;
    short*       ws          = (short*)d_ws;   // needs 128 KB

    prep_weights<<<128, 256, 0, stream>>>(W1, W2, ws);
    mlip_fused<<<NB, 1024, 0, stream>>>(atomic_nums, coords, embed_table,
                                        b1, b2, Wo, bo, centers, ws, out);
}

// Round 5
// 28.234 us; speedup vs baseline: 1.0498x; 1.0498x over previous
//
#include <hip/hip_runtime.h>
#include <math.h>

namespace {
constexpr int NB   = 256;
constexpr int NA   = 64;
constexpr int EMBD = 64;
constexpr int HIDD = 128;
constexpr int OUTD = 512;
constexpr int FPS  = 136;   // short-stride for bf16 LDS tiles (272 B rows: conflict-free frag reads)

typedef __attribute__((ext_vector_type(8))) short bfrag8;   // 8 bf16 = 4 VGPRs
typedef __attribute__((ext_vector_type(4))) float floatx4;  // MFMA accumulator

__device__ __forceinline__ unsigned short bf16_rne(float f) {
    unsigned u = __float_as_uint(f);
    u += 0x7fffu + ((u >> 16) & 1u);
    return (unsigned short)(u >> 16);
}

// branch-free exact-GELU: erf via Abramowitz-Stegun 7.1.26 (|err| <= 1.5e-7)
__device__ __forceinline__ float gelu_fast(float x) {
    const float ax = fabsf(x) * 0.7071067811865475f;
    const float t  = __builtin_amdgcn_rcpf(fmaf(0.3275911f, ax, 1.0f));
    float p = fmaf(1.061405429f, t, -1.453152027f);
    p = fmaf(p, t, 1.421413741f);
    p = fmaf(p, t, -0.284496736f);
    p = fmaf(p, t, 0.254829592f);
    p = p * t;
    const float e = __builtin_amdgcn_exp2f(-1.4426950408889634f * ax * ax);
    const float erfx = copysignf(fmaf(-p, e, 1.0f), x);
    const float hx   = 0.5f * x;
    return fmaf(hx, erfx, hx);
}

// W-fragment LDS layout (shorts): hi at (fg*64+ls)*8 + r, lo at +16384,
// fg = ks*8 + tile (0..31);  element = W[ks*32+(ls>>4)*8+r][tile*16+(ls&15)]
// (same mapping as the round-3/4 prep kernel, HW-validated)

__global__ __launch_bounds__(1024, 1)
void mlip_fused(const int*   __restrict__ atomic_nums,
                const float* __restrict__ coords,
                const float* __restrict__ embed_table,
                const float* __restrict__ W1, const float* __restrict__ b1,
                const float* __restrict__ W2, const float* __restrict__ b2,
                const float* __restrict__ Wo, const float* __restrict__ bo,
                const float* __restrict__ centers,
                float*       __restrict__ out)
{
    const int b    = blockIdx.x;
    const int tid  = threadIdx.x;
    const int lane = tid & 63;
    const int wid  = tid >> 6;          // 16 waves

    __shared__ float s_dist[NA * NA];                  // 16 KB (front only)
    __shared__ short s_w[2 * 16384];                   // 64 KB: W frags hi|lo (W1 then W2)
    __shared__ short s_fhi[NA][FPS], s_flo[NA][FPS];   // feat bf16 hi/lo (34 KB)
    __shared__ short s_hhi[NA][FPS], s_hlo[NA][FPS];   // h    bf16 hi/lo (34 KB)
    __shared__ float s_mol[4][HIDD];
    __shared__ float s_molv[HIDD];

    // ---- tiling ids
    const int wm      = wid & 3, wn = wid >> 2;
    const int lrow    = lane & 15, g4 = lane >> 4;
    const int arow    = (wm << 4) + lrow;
    const int drow0   = (wm << 4) + (g4 << 2);
    const int colbase = (wn << 5) + lrow;

    // ---- tail ids (lane-pair split) + preloads
    const int   colT = tid >> 1, kh = tid & 1;
    const float bo_r = bo[colT];
    const float b1a  = b1[colbase];
    const float b1b  = b1[colbase + 16];
    const float b2r  = b2[tid & 127];
    const float c    = centers[lane];

    // ---- W-conversion slot indices (2 assignments/thread; wave-uniform fg)
    int fgA[2], k0A[2], nA[2];
#pragma unroll
    for (int a = 0; a < 2; ++a) {
        const int slot = (a << 10) + tid;
        const int fg = slot >> 6, ls = slot & 63;
        fgA[a] = fg;
        k0A[a] = ((fg >> 3) << 5) + ((ls >> 4) << 3);
        nA[a]  = ((fg & 7) << 4) + (ls & 15);
    }

    // ---- issue W1 loads early (consumed mid-front)
    float w1v[16];
#pragma unroll
    for (int a = 0; a < 2; ++a) {
        const float* src = W1 + (size_t)k0A[a] * HIDD + nA[a];
#pragma unroll
        for (int r = 0; r < 8; ++r) w1v[a * 8 + r] = src[(size_t)r * HIDD];
    }

    // ---- coords + embedding
    const float* cbase = coords + (size_t)b * NA * 3;
    const float cx = cbase[lane * 3 + 0];
    const float cy = cbase[lane * 3 + 1];
    const float cz = cbase[lane * 3 + 2];
    {
        const int i = tid >> 4, e4 = (tid & 15) << 2;
        const int z = atomic_nums[b * NA + i];
        const float4 ev = *(const float4*)(embed_table + (size_t)z * EMBD + e4);
        short4 h4, l4;
        const float v[4] = {ev.x, ev.y, ev.z, ev.w};
        short* hp = (short*)&h4; short* lp = (short*)&l4;
#pragma unroll
        for (int q = 0; q < 4; ++q) {
            const unsigned short h = bf16_rne(v[q]);
            hp[q] = (short)h;
            lp[q] = (short)bf16_rne(v[q] - __uint_as_float((unsigned)h << 16));
        }
        *(short4*)&s_fhi[i][e4] = h4;
        *(short4*)&s_flo[i][e4] = l4;
    }

    // ---- dist rows this wave will itself consume (within-wave dep only)
#pragma unroll
    for (int it = 0; it < 4; ++it) {
        const int i = wid + (it << 4);
        const float xi = __shfl(cx, i, 64);
        const float yi = __shfl(cy, i, 64);
        const float zi = __shfl(cz, i, 64);
        const float dx = xi - cx, dy = yi - cy, dz = zi - cz;
        const float sq = dx * dx + dy * dy + dz * dz;
        s_dist[(i << 6) + lane] = sq > 0.0f ? sqrtf(sq) : 0.0f;
    }

    // ---- convert W1 -> s_w (hi/lo, b128 stores)
#pragma unroll
    for (int a = 0; a < 2; ++a) {
        unsigned Hu[4], Lu[4];
#pragma unroll
        for (int p = 0; p < 4; ++p) {
            const float x = w1v[a * 8 + 2 * p], y = w1v[a * 8 + 2 * p + 1];
            unsigned h;
            asm("v_cvt_pk_bf16_f32 %0, %1, %2" : "=v"(h) : "v"(x), "v"(y));
            const float hx = __uint_as_float(h << 16);
            const float hy = __uint_as_float(h & 0xffff0000u);
            unsigned l;
            asm("v_cvt_pk_bf16_f32 %0, %1, %2" : "=v"(l) : "v"(x - hx), "v"(y - hy));
            Hu[p] = h; Lu[p] = l;
        }
        const int base = (fgA[a] << 9) + (((a << 10) + tid) & 63) * 8;
        *(uint4*)&s_w[base]         = make_uint4(Hu[0], Hu[1], Hu[2], Hu[3]);
        *(uint4*)&s_w[16384 + base] = make_uint4(Lu[0], Lu[1], Lu[2], Lu[3]);
    }

    // ---- gaussian smear, mean over j -> s_f[:, 64:128]
    {
        const float K2  = -2.8853900817779268f;   // -2*log2(e)
        const float nu2 = -2.0f * K2 * c;
        const float vc  = K2 * c * c;
#pragma unroll
        for (int it = 0; it < 4; ++it) {
            const int i = wid + (it << 4);
            const float* drow = &s_dist[i << 6];
            float a0 = 0.f, a1 = 0.f, a2 = 0.f, a3 = 0.f;
#pragma unroll
            for (int j4 = 0; j4 < NA; j4 += 4) {
                const float4 d4 = *(const float4*)(drow + j4);
                a0 += __builtin_amdgcn_exp2f(fmaf(d4.x, fmaf(K2, d4.x, nu2), vc));
                a1 += __builtin_amdgcn_exp2f(fmaf(d4.y, fmaf(K2, d4.y, nu2), vc));
                a2 += __builtin_amdgcn_exp2f(fmaf(d4.z, fmaf(K2, d4.z, nu2), vc));
                a3 += __builtin_amdgcn_exp2f(fmaf(d4.w, fmaf(K2, d4.w, nu2), vc));
            }
            const float acc = ((a0 + a1) + (a2 + a3)) * (1.0f / 64.0f);
            const unsigned short h = bf16_rne(acc);
            s_fhi[i][EMBD + lane] = (short)h;
            s_flo[i][EMBD + lane] =
                (short)bf16_rne(acc - __uint_as_float((unsigned)h << 16));
        }
    }

    // ---- issue W2 loads now; they complete during stage 3
    float w2v[16];
#pragma unroll
    for (int a = 0; a < 2; ++a) {
        const float* src = W2 + (size_t)k0A[a] * HIDD + nA[a];
#pragma unroll
        for (int r = 0; r < 8; ++r) w2v[a * 8 + r] = src[(size_t)r * HIDD];
    }
    __syncthreads();                                   // barrier 1: feat + W1 ready

    // ---- stage 3: h = gelu(feat @ W1 + b1); A and B frags both from LDS
    {
        floatx4 acc0 = {0,0,0,0}, acc1 = {0,0,0,0};
#pragma unroll
        for (int ks = 0; ks < 4; ++ks) {
            const int k0 = (ks << 5) + (g4 << 3);
            const bfrag8 ahi = *(const bfrag8*)&s_fhi[arow][k0];
            const bfrag8 alo = *(const bfrag8*)&s_flo[arow][k0];
#pragma unroll
            for (int nt = 0; nt < 2; ++nt) {
                const int base = ((((ks << 3) + (wn << 1) + nt) << 6) + lane) << 3;
                const bfrag8 bhi = *(const bfrag8*)&s_w[base];
                const bfrag8 blo = *(const bfrag8*)&s_w[16384 + base];
                floatx4 a = nt ? acc1 : acc0;
                a = __builtin_amdgcn_mfma_f32_16x16x32_bf16(ahi, bhi, a, 0, 0, 0);
                a = __builtin_amdgcn_mfma_f32_16x16x32_bf16(ahi, blo, a, 0, 0, 0);
                a = __builtin_amdgcn_mfma_f32_16x16x32_bf16(alo, bhi, a, 0, 0, 0);
                if (nt) acc1 = a; else acc0 = a;
            }
        }
#pragma unroll
        for (int nt = 0; nt < 2; ++nt) {
            const int col = colbase + (nt << 4);
            const float bb = nt ? b1b : b1a;
            const floatx4 a = nt ? acc1 : acc0;
#pragma unroll
            for (int r = 0; r < 4; ++r) {
                const float v = gelu_fast(a[r] + bb);
                const unsigned short h = bf16_rne(v);
                s_hhi[drow0 + r][col] = (short)h;
                s_hlo[drow0 + r][col] =
                    (short)bf16_rne(v - __uint_as_float((unsigned)h << 16));
            }
        }
    }
    __syncthreads();                                   // barrier 2: h ready, W1 reads done

    // ---- convert W2 -> s_w (overwrites W1 frags)
#pragma unroll
    for (int a = 0; a < 2; ++a) {
        unsigned Hu[4], Lu[4];
#pragma unroll
        for (int p = 0; p < 4; ++p) {
            const float x = w2v[a * 8 + 2 * p], y = w2v[a * 8 + 2 * p + 1];
            unsigned h;
            asm("v_cvt_pk_bf16_f32 %0, %1, %2" : "=v"(h) : "v"(x), "v"(y));
            const float hx = __uint_as_float(h << 16);
            const float hy = __uint_as_float(h & 0xffff0000u);
            unsigned l;
            asm("v_cvt_pk_bf16_f32 %0, %1, %2" : "=v"(l) : "v"(x - hx), "v"(y - hy));
            Hu[p] = h; Lu[p] = l;
        }
        const int base = (fgA[a] << 9) + (((a << 10) + tid) & 63) * 8;
        *(uint4*)&s_w[base]         = make_uint4(Hu[0], Hu[1], Hu[2], Hu[3]);
        *(uint4*)&s_w[16384 + base] = make_uint4(Lu[0], Lu[1], Lu[2], Lu[3]);
    }
    __syncthreads();                                   // barrier 2b: W2 frags ready

    // ---- stage 4: h2 = h @ W2, atom-sum folded into shuffle reduction
    float wo_r[64];
    {
        floatx4 acc0 = {0,0,0,0}, acc1 = {0,0,0,0};
#pragma unroll
        for (int ks = 0; ks < 4; ++ks) {
            const int k0 = (ks << 5) + (g4 << 3);
            const bfrag8 ahi = *(const bfrag8*)&s_hhi[arow][k0];
            const bfrag8 alo = *(const bfrag8*)&s_hlo[arow][k0];
#pragma unroll
            for (int nt = 0; nt < 2; ++nt) {
                const int base = ((((ks << 3) + (wn << 1) + nt) << 6) + lane) << 3;
                const bfrag8 bhi = *(const bfrag8*)&s_w[base];
                const bfrag8 blo = *(const bfrag8*)&s_w[16384 + base];
                floatx4 a = nt ? acc1 : acc0;
                a = __builtin_amdgcn_mfma_f32_16x16x32_bf16(ahi, bhi, a, 0, 0, 0);
                a = __builtin_amdgcn_mfma_f32_16x16x32_bf16(ahi, blo, a, 0, 0, 0);
                a = __builtin_amdgcn_mfma_f32_16x16x32_bf16(alo, bhi, a, 0, 0, 0);
                if (nt) acc1 = a; else acc0 = a;
            }
        }

        // Wo prefetch: latency hides under reduce + barriers + stage 5
        {
            const float* wop = Wo + ((size_t)(kh << 6)) * OUTD + colT;
#pragma unroll
            for (int k = 0; k < 64; ++k) wo_r[k] = wop[(size_t)k * OUTD];
        }

#pragma unroll
        for (int nt = 0; nt < 2; ++nt) {
            const floatx4 a = nt ? acc1 : acc0;
            float s = a[0] + a[1] + a[2] + a[3];
            s += __shfl_xor(s, 16, 64);
            s += __shfl_xor(s, 32, 64);
            if (lane < 16) s_mol[wm][colbase + (nt << 4)] = s;
        }
    }
    __syncthreads();                                   // barrier 3

    // ---- stage 5: mol = mean + b2
    if (tid < HIDD)
        s_molv[tid] = (s_mol[0][tid] + s_mol[1][tid] + s_mol[2][tid] + s_mol[3][tid])
                      * (1.0f / 64.0f) + b2r;
    __syncthreads();                                   // barrier 4

    // ---- stage 6: out = mol @ Wo + bo; lane-pair K-split, shfl combine (no barrier)
    {
        const float* mp = &s_molv[kh << 6];
        float a = 0.0f;
#pragma unroll
        for (int k = 0; k < 64; k += 4) {
            const float4 m4 = *(const float4*)(mp + k);
            a = fmaf(m4.x, wo_r[k + 0], a);
            a = fmaf(m4.y, wo_r[k + 1], a);
            a = fmaf(m4.z, wo_r[k + 2], a);
            a = fmaf(m4.w, wo_r[k + 3], a);
        }
        a += __shfl_xor(a, 1, 64);
        if (kh == 0)
            out[(size_t)b * OUTD + colT] = a + bo_r;
    }
}
} // namespace

extern "C" void kernel_launch(void* const* d_in, const int* in_sizes, int n_in,
                              void* d_out, int out_size, void* d_ws, size_t ws_size,
                              hipStream_t stream) {
    const int*   atomic_nums = (const int*)  d_in[0];
    const float* coords      = (const float*)d_in[1];
    const float* embed_table = (const float*)d_in[2];
    const float* W1          = (const float*)d_in[3];
    const float* b1          = (const float*)d_in[4];
    const float* W2          = (const float*)d_in[5];
    const float* b2          = (const float*)d_in[6];
    const float* Wo          = (const float*)d_in[7];
    const float* bo          = (const float*)d_in[8];
    const float* centers     = (const float*)d_in[9];
    float*       out         = (float*)d_out;

    mlip_fused<<<NB, 1024, 0, stream>>>(atomic_nums, coords, embed_table,
                                        W1, b1, W2, b2, Wo, bo, centers, out);
}

// Round 6
// 26.366 us; speedup vs baseline: 1.1242x; 1.0709x over previous
//
#include <hip/hip_runtime.h>
#include <math.h>

namespace {
constexpr int NB   = 256;
constexpr int NA   = 64;
constexpr int EMBD = 64;
constexpr int HIDD = 128;
constexpr int OUTD = 512;
constexpr int FPS  = 136;   // short-stride for bf16 LDS tiles (272 B rows: conflict-free frag reads)

typedef __attribute__((ext_vector_type(8))) short bfrag8;   // 8 bf16 = 4 VGPRs
typedef __attribute__((ext_vector_type(4))) float floatx4;  // MFMA accumulator

__device__ __forceinline__ unsigned short bf16_rne(float f) {
    unsigned u = __float_as_uint(f);
    u += 0x7fffu + ((u >> 16) & 1u);
    return (unsigned short)(u >> 16);
}

// branch-free exact-GELU: erf via Abramowitz-Stegun 7.1.26 (|err| <= 1.5e-7)
__device__ __forceinline__ float gelu_fast(float x) {
    const float ax = fabsf(x) * 0.7071067811865475f;
    const float t  = __builtin_amdgcn_rcpf(fmaf(0.3275911f, ax, 1.0f));
    float p = fmaf(1.061405429f, t, -1.453152027f);
    p = fmaf(p, t, 1.421413741f);
    p = fmaf(p, t, -0.284496736f);
    p = fmaf(p, t, 0.254829592f);
    p = p * t;
    const float e = __builtin_amdgcn_exp2f(-1.4426950408889634f * ax * ax);
    const float erfx = copysignf(fmaf(-p, e, 1.0f), x);
    const float hx   = 0.5f * x;
    return fmaf(hx, erfx, hx);
}

// W1-fragment LDS layout (shorts): hi at (fg*64+ls)*8 + r, lo at +16384,
// fg = ks*8 + tile;  element = W1[ks*32+(ls>>4)*8+r][tile*16+(ls&15)]

__global__ __launch_bounds__(1024, 1)
void mlip_fused(const int*   __restrict__ atomic_nums,
                const float* __restrict__ coords,
                const float* __restrict__ embed_table,
                const float* __restrict__ W1, const float* __restrict__ b1,
                const float* __restrict__ W2, const float* __restrict__ b2,
                const float* __restrict__ Wo, const float* __restrict__ bo,
                const float* __restrict__ centers,
                float*       __restrict__ out)
{
    const int b    = blockIdx.x;
    const int tid  = threadIdx.x;
    const int lane = tid & 63;
    const int wid  = tid >> 6;          // 16 waves

    __shared__ float s_dist[NA * NA];                  // 16 KB; reused as GEMV partial buf
    __shared__ short s_w[2 * 16384];                   // 64 KB: W1 frags hi|lo
    __shared__ short s_fhi[NA][FPS], s_flo[NA][FPS];   // feat bf16 hi/lo (34 KB)
    __shared__ float s_mol[4][HIDD];                   // per-wm column sums of gelu out
    __shared__ float s_molv[HIDD];

    // ---- tiling ids
    const int wm      = wid & 3, wn = wid >> 2;
    const int lrow    = lane & 15, g4 = lane >> 4;
    const int arow    = (wm << 4) + lrow;
    const int colbase = (wn << 5) + lrow;

    // ---- GEMV ids (mol = colmean(G) @ W2 + b2): col + K-chunk per thread
    const int gcol = tid & 127, kc = tid >> 7;         // kc in [0,8)
    // ---- tail ids (lane-pair K-split over Wo)
    const int colT = tid >> 1, kh = tid & 1;

    // ---- early preloads
    const float bo_r = bo[colT];
    const float b1a  = b1[colbase];
    const float b1b  = b1[colbase + 16];
    const float b2r  = b2[gcol];
    const float c    = centers[lane];

    // W2 rows for this thread's GEMV chunk (f32, exact; L2-hot across blocks)
    float w2r[16];
    {
        const float* src = W2 + (size_t)(kc << 4) * HIDD + gcol;
#pragma unroll
        for (int q = 0; q < 16; ++q) w2r[q] = src[(size_t)q * HIDD];
    }

    // ---- W1-conversion slot indices (2 assignments/thread)
    int fgA[2], k0A[2], nA[2];
#pragma unroll
    for (int a = 0; a < 2; ++a) {
        const int slot = (a << 10) + tid;
        const int fg = slot >> 6, ls = slot & 63;
        fgA[a] = fg;
        k0A[a] = ((fg >> 3) << 5) + ((ls >> 4) << 3);
        nA[a]  = ((fg & 7) << 4) + (ls & 15);
    }
    float w1v[16];
#pragma unroll
    for (int a = 0; a < 2; ++a) {
        const float* src = W1 + (size_t)k0A[a] * HIDD + nA[a];
#pragma unroll
        for (int r = 0; r < 8; ++r) w1v[a * 8 + r] = src[(size_t)r * HIDD];
    }

    // ---- coords + embedding
    const float* cbase = coords + (size_t)b * NA * 3;
    const float cx = cbase[lane * 3 + 0];
    const float cy = cbase[lane * 3 + 1];
    const float cz = cbase[lane * 3 + 2];
    {
        const int i = tid >> 4, e4 = (tid & 15) << 2;
        const int z = atomic_nums[b * NA + i];
        const float4 ev = *(const float4*)(embed_table + (size_t)z * EMBD + e4);
        short4 h4, l4;
        const float v[4] = {ev.x, ev.y, ev.z, ev.w};
        short* hp = (short*)&h4; short* lp = (short*)&l4;
#pragma unroll
        for (int q = 0; q < 4; ++q) {
            const unsigned short h = bf16_rne(v[q]);
            hp[q] = (short)h;
            lp[q] = (short)bf16_rne(v[q] - __uint_as_float((unsigned)h << 16));
        }
        *(short4*)&s_fhi[i][e4] = h4;
        *(short4*)&s_flo[i][e4] = l4;
    }

    // ---- dist rows this wave will itself consume (within-wave dep only)
#pragma unroll
    for (int it = 0; it < 4; ++it) {
        const int i = wid + (it << 4);
        const float xi = __shfl(cx, i, 64);
        const float yi = __shfl(cy, i, 64);
        const float zi = __shfl(cz, i, 64);
        const float dx = xi - cx, dy = yi - cy, dz = zi - cz;
        const float sq = dx * dx + dy * dy + dz * dz;
        s_dist[(i << 6) + lane] = sq > 0.0f ? sqrtf(sq) : 0.0f;
    }

    // ---- convert W1 -> s_w (hi/lo, b128 stores)
#pragma unroll
    for (int a = 0; a < 2; ++a) {
        unsigned Hu[4], Lu[4];
#pragma unroll
        for (int p = 0; p < 4; ++p) {
            const float x = w1v[a * 8 + 2 * p], y = w1v[a * 8 + 2 * p + 1];
            unsigned h;
            asm("v_cvt_pk_bf16_f32 %0, %1, %2" : "=v"(h) : "v"(x), "v"(y));
            const float hx = __uint_as_float(h << 16);
            const float hy = __uint_as_float(h & 0xffff0000u);
            unsigned l;
            asm("v_cvt_pk_bf16_f32 %0, %1, %2" : "=v"(l) : "v"(x - hx), "v"(y - hy));
            Hu[p] = h; Lu[p] = l;
        }
        const int base = (fgA[a] << 9) + (((a << 10) + tid) & 63) * 8;
        *(uint4*)&s_w[base]         = make_uint4(Hu[0], Hu[1], Hu[2], Hu[3]);
        *(uint4*)&s_w[16384 + base] = make_uint4(Lu[0], Lu[1], Lu[2], Lu[3]);
    }

    // ---- gaussian smear, mean over j -> s_f[:, 64:128]
    {
        const float K2  = -2.8853900817779268f;   // -2*log2(e)
        const float nu2 = -2.0f * K2 * c;
        const float vc  = K2 * c * c;
#pragma unroll
        for (int it = 0; it < 4; ++it) {
            const int i = wid + (it << 4);
            const float* drow = &s_dist[i << 6];
            float a0 = 0.f, a1 = 0.f, a2 = 0.f, a3 = 0.f;
#pragma unroll
            for (int j4 = 0; j4 < NA; j4 += 4) {
                const float4 d4 = *(const float4*)(drow + j4);
                a0 += __builtin_amdgcn_exp2f(fmaf(d4.x, fmaf(K2, d4.x, nu2), vc));
                a1 += __builtin_amdgcn_exp2f(fmaf(d4.y, fmaf(K2, d4.y, nu2), vc));
                a2 += __builtin_amdgcn_exp2f(fmaf(d4.z, fmaf(K2, d4.z, nu2), vc));
                a3 += __builtin_amdgcn_exp2f(fmaf(d4.w, fmaf(K2, d4.w, nu2), vc));
            }
            const float acc = ((a0 + a1) + (a2 + a3)) * (1.0f / 64.0f);
            const unsigned short h = bf16_rne(acc);
            s_fhi[i][EMBD + lane] = (short)h;
            s_flo[i][EMBD + lane] =
                (short)bf16_rne(acc - __uint_as_float((unsigned)h << 16));
        }
    }
    __syncthreads();                                   // barrier 1: feat + W1 frags ready

    // ---- stage 3: G = gelu(feat @ W1 + b1); column sums of G folded in-register
    float wo_a[32];
    {
        floatx4 acc0 = {0,0,0,0}, acc1 = {0,0,0,0};
#pragma unroll
        for (int ks = 0; ks < 4; ++ks) {
            const int k0 = (ks << 5) + (g4 << 3);
            const bfrag8 ahi = *(const bfrag8*)&s_fhi[arow][k0];
            const bfrag8 alo = *(const bfrag8*)&s_flo[arow][k0];
#pragma unroll
            for (int nt = 0; nt < 2; ++nt) {
                const int base = ((((ks << 3) + (wn << 1) + nt) << 6) + lane) << 3;
                const bfrag8 bhi = *(const bfrag8*)&s_w[base];
                const bfrag8 blo = *(const bfrag8*)&s_w[16384 + base];
                floatx4 a = nt ? acc1 : acc0;
                a = __builtin_amdgcn_mfma_f32_16x16x32_bf16(ahi, bhi, a, 0, 0, 0);
                a = __builtin_amdgcn_mfma_f32_16x16x32_bf16(ahi, blo, a, 0, 0, 0);
                a = __builtin_amdgcn_mfma_f32_16x16x32_bf16(alo, bhi, a, 0, 0, 0);
                if (nt) acc1 = a; else acc0 = a;
            }
        }

        // issue first half of Wo prefetch (covers GEMV + 2 barriers)
        {
            const float* wop = Wo + ((size_t)(kh << 6)) * OUTD + colT;
#pragma unroll
            for (int k = 0; k < 32; ++k) wo_a[k] = wop[(size_t)k * OUTD];
        }

        // gelu + column reduce: rows g4*4+r summed in-lane, then across g4 groups
#pragma unroll
        for (int nt = 0; nt < 2; ++nt) {
            const float bb = nt ? b1b : b1a;
            const floatx4 a = nt ? acc1 : acc0;
            float s = gelu_fast(a[0] + bb) + gelu_fast(a[1] + bb)
                    + gelu_fast(a[2] + bb) + gelu_fast(a[3] + bb);
            s += __shfl_xor(s, 16, 64);
            s += __shfl_xor(s, 32, 64);
            if (lane < 16) s_mol[wm][colbase + (nt << 4)] = s;   // col-sum of 16 rows
        }
    }
    __syncthreads();                                   // barrier 2: s_mol ready

    // ---- GEMV: mol_raw[col] = sum_k (sum_wm s_mol[wm][k]) * W2[k][col]
    float wo_b[32];
    {
        float acc = 0.0f;
        const int kb = kc << 4;
#pragma unroll
        for (int q = 0; q < 16; ++q) {
            const int k = kb + q;
            const float hk = (s_mol[0][k] + s_mol[1][k])
                           + (s_mol[2][k] + s_mol[3][k]);   // wave-uniform broadcasts
            acc = fmaf(hk, w2r[q], acc);
        }
        s_dist[(kc << 7) + gcol] = acc;                // s_dist reused as partial buf

        // issue second half of Wo prefetch
        const float* wop = Wo + ((size_t)((kh << 6) + 32)) * OUTD + colT;
#pragma unroll
        for (int k = 0; k < 32; ++k) wo_b[k] = wop[(size_t)k * OUTD];
    }
    __syncthreads();                                   // barrier 3: partials ready

    // ---- mol = colsum/64 + b2
    if (tid < HIDD) {
        float m = 0.0f;
#pragma unroll
        for (int p = 0; p < 8; ++p) m += s_dist[(p << 7) + tid];
        s_molv[tid] = m * (1.0f / 64.0f) + b2r;
    }
    __syncthreads();                                   // barrier 4: molv ready

    // ---- tail: out = mol @ Wo + bo; lane-pair K-split, shfl combine
    {
        const float* mp = &s_molv[kh << 6];
        float a = 0.0f;
#pragma unroll
        for (int k = 0; k < 32; ++k) a = fmaf(mp[k], wo_a[k], a);
#pragma unroll
        for (int k = 0; k < 32; ++k) a = fmaf(mp[32 + k], wo_b[k], a);
        a += __shfl_xor(a, 1, 64);
        if (kh == 0)
            out[(size_t)b * OUTD + colT] = a + bo_r;
    }
}
} // namespace

extern "C" void kernel_launch(void* const* d_in, const int* in_sizes, int n_in,
                              void* d_out, int out_size, void* d_ws, size_t ws_size,
                              hipStream_t stream) {
    const int*   atomic_nums = (const int*)  d_in[0];
    const float* coords      = (const float*)d_in[1];
    const float* embed_table = (const float*)d_in[2];
    const float* W1          = (const float*)d_in[3];
    const float* b1          = (const float*)d_in[4];
    const float* W2          = (const float*)d_in[5];
    const float* b2          = (const float*)d_in[6];
    const float* Wo          = (const float*)d_in[7];
    const float* bo          = (const float*)d_in[8];
    const float* centers     = (const float*)d_in[9];
    float*       out         = (float*)d_out;

    mlip_fused<<<NB, 1024, 0, stream>>>(atomic_nums, coords, embed_table,
                                        W1, b1, W2, b2, Wo, bo, centers, out);
}